// Round 1
// baseline (1018.714 us; speedup 1.0000x reference)
//
#include <hip/hip_runtime.h>
#include <hip/hip_bf16.h>
#include <cstdint>
#include <cstddef>

// LearnableUpsampler: quant -> convT(K=4,s=2) -> quant -> conv7+silu -> quant -> conv7 + res -> LN
// Round 0: correctness-first fp32 direct convs. Ternary weights packed int8,
// activations quantized int8 + per-token invscale (bit-exact vs reference since
// absmax/rint are order-independent). Future: i8 MFMA GEMM path.

#define B_ 2
#define T_ 2048
#define L_ 4096
#define C_ 512

static constexpr int NUP = 512 * 512 * 4;  // w_up elements
static constexpr int NR  = 512 * 512 * 7;  // w_r1 / w_r2 elements

// ---------------- reductions ----------------

__device__ inline float block_reduce_sum_256(float v) {
  #pragma unroll
  for (int off = 32; off > 0; off >>= 1) v += __shfl_down(v, off, 64);
  __shared__ float s[4];
  __syncthreads();  // protect shared from a previous call
  if ((threadIdx.x & 63) == 0) s[threadIdx.x >> 6] = v;
  __syncthreads();
  return (s[0] + s[1]) + (s[2] + s[3]);
}

// ---------------- weight abs-sum ----------------

__global__ void abssum_kernel(const float* __restrict__ w, int n, float* __restrict__ out) {
  int idx = blockIdx.x * 256 + threadIdx.x;
  float s = 0.f;
  for (int i = idx; i < n; i += gridDim.x * 256) s += fabsf(w[i]);
  s = block_reduce_sum_256(s);
  if (threadIdx.x == 0) atomicAdd(out, s);
}

// ---------------- ternarize + repack ----------------
// w_up (ci, co, 4) -> out[(ci*512+co)*4 + k] int8
__global__ void tern_up_kernel(const float* __restrict__ w, int8_t* __restrict__ o,
                               const float* __restrict__ wsum) {
  int idx = blockIdx.x * 256 + threadIdx.x;
  if (idx >= NUP) return;
  float mean = wsum[0] * (1.0f / (float)NUP);
  float M = fmaxf(mean, 1e-5f);
  float scale = 1.0f / M;
  float t = rintf(w[idx] * scale);
  t = fminf(fmaxf(t, -1.f), 1.f);
  int ci = idx >> 11;          // /2048
  int rem = idx & 2047;
  int co = rem >> 2;
  int k = rem & 3;
  o[(((size_t)ci << 9) + co) * 4 + k] = (int8_t)t;
}

// w_r (co, ci, 7) -> out[(ci*512+co)*8 + k] int8, k=7 slot zero-padded
__global__ void tern_7_kernel(const float* __restrict__ w, int8_t* __restrict__ o,
                              const float* __restrict__ wsum, int widx) {
  int idx = blockIdx.x * 256 + threadIdx.x;
  if (idx >= NR) return;
  float mean = wsum[widx] * (1.0f / (float)NR);
  float M = fmaxf(mean, 1e-5f);
  float scale = 1.0f / M;
  float t = rintf(w[idx] * scale);
  t = fminf(fmaxf(t, -1.f), 1.f);
  int co = idx / 3584;         // /(512*7)
  int rem = idx - co * 3584;
  int ci = rem / 7;
  int k = rem - ci * 7;
  size_t base = (((size_t)ci << 9) + co) * 8;
  o[base + k] = (int8_t)t;
  if (k == 0) o[base + 7] = 0;  // pad (ws re-poisoned 0xAA every call!)
}

// ---------------- per-token activation quant ----------------
// one block (256 thr) per token, row of 512 floats
__global__ void act_quant_kernel(const float* __restrict__ x, int8_t* __restrict__ q,
                                 float* __restrict__ inv) {
  int tok = blockIdx.x;
  const float* row = x + (size_t)tok * C_;
  int tid = threadIdx.x;
  float v0 = row[tid];
  float v1 = row[tid + 256];
  float m = fmaxf(fabsf(v0), fabsf(v1));
  #pragma unroll
  for (int off = 32; off > 0; off >>= 1) m = fmaxf(m, __shfl_down(m, off, 64));
  __shared__ float s[4];
  if ((tid & 63) == 0) s[tid >> 6] = m;
  __syncthreads();
  m = fmaxf(fmaxf(s[0], s[1]), fmaxf(s[2], s[3]));
  float scale = 127.0f / fmaxf(m, 1e-5f);   // exact: max is order-independent
  float q0 = fminf(fmaxf(rintf(v0 * scale), -128.f), 127.f);
  float q1 = fminf(fmaxf(rintf(v1 * scale), -128.f), 127.f);
  size_t base = (size_t)tok * C_;
  q[base + tid] = (int8_t)q0;
  q[base + tid + 256] = (int8_t)q1;
  if (tid == 0) inv[tok] = 1.0f / scale;
}

// ---------------- transposed conv (K=4, stride=2, pad=1) ----------------
// y[co,t] = sum_ci sum_{k=t+1-2s in [0,4)} x[ci,s]*w[ci,co,k]
// block: 8 output tokens x 512 co; thread: 2 co x 8 tokens
__launch_bounds__(256)
__global__ void convt_kernel(const int8_t* __restrict__ qx, const float* __restrict__ invx,
                             const int8_t* __restrict__ wq, const float* __restrict__ wsum,
                             const float* __restrict__ bias, float* __restrict__ h) {
  __shared__ float a[6][C_];
  int b = blockIdx.x >> 9;
  int t0 = (blockIdx.x & 511) << 3;
  int sbase = (t0 >> 1) - 1;
  int tid = threadIdx.x;
  for (int i = tid; i < 6 * C_; i += 256) {
    int row = i >> 9;
    int ci = i & 511;
    int s = sbase + row;
    float v = 0.f;
    if (s >= 0 && s < T_) v = (float)qx[(((size_t)b * T_ + s) << 9) + ci] * invx[b * T_ + s];
    a[row][ci] = v;
  }
  __syncthreads();
  int co = tid * 2;
  float acc0[8], acc1[8];
  #pragma unroll
  for (int j = 0; j < 8; ++j) { acc0[j] = 0.f; acc1[j] = 0.f; }
  for (int ci = 0; ci < C_; ++ci) {
    int2 wv = *(const int2*)(wq + ((((size_t)ci << 9) + co) << 2));
    float w0[4], w1[4];
    #pragma unroll
    for (int k = 0; k < 4; ++k) {
      w0[k] = (float)(int8_t)(wv.x >> (8 * k));
      w1[k] = (float)(int8_t)(wv.y >> (8 * k));
    }
    float av[6];
    #pragma unroll
    for (int r = 0; r < 6; ++r) av[r] = a[r][ci];
    #pragma unroll
    for (int j = 0; j < 8; ++j) {
      if (j & 1) {
        int r = (j + 1) >> 1;
        acc0[j] = fmaf(av[r + 1], w0[0], acc0[j]);
        acc0[j] = fmaf(av[r], w0[2], acc0[j]);
        acc1[j] = fmaf(av[r + 1], w1[0], acc1[j]);
        acc1[j] = fmaf(av[r], w1[2], acc1[j]);
      } else {
        int r = j >> 1;
        acc0[j] = fmaf(av[r + 1], w0[1], acc0[j]);
        acc0[j] = fmaf(av[r], w0[3], acc0[j]);
        acc1[j] = fmaf(av[r + 1], w1[1], acc1[j]);
        acc1[j] = fmaf(av[r], w1[3], acc1[j]);
      }
    }
  }
  float mean = wsum[0] * (1.0f / (float)NUP);
  float M = fmaxf(mean, 1e-5f);
  float wscale = 1.0f / M;
  float dq = 1.0f / wscale;
  float b0 = bias[co], b1 = bias[co + 1];
  #pragma unroll
  for (int j = 0; j < 8; ++j) {
    size_t idx = (((size_t)b * L_ + t0 + j) << 9) + co;
    h[idx] = acc0[j] * dq + b0;
    h[idx + 1] = acc1[j] * dq + b1;
  }
}

// ---------------- conv K=7 pad=3 (+optional silu, +optional residual) ----------------
__launch_bounds__(256)
__global__ void conv7_kernel(const int8_t* __restrict__ q, const float* __restrict__ invv,
                             const int8_t* __restrict__ wq, const float* __restrict__ wsum,
                             int widx, const float* __restrict__ bias,
                             const float* __restrict__ res, int do_silu,
                             float* __restrict__ out) {
  __shared__ float a[14][C_];
  int b = blockIdx.x >> 9;
  int t0 = (blockIdx.x & 511) << 3;
  int tid = threadIdx.x;
  for (int i = tid; i < 14 * C_; i += 256) {
    int row = i >> 9;
    int ci = i & 511;
    int t = t0 - 3 + row;
    float v = 0.f;
    if (t >= 0 && t < L_) v = (float)q[(((size_t)b * L_ + t) << 9) + ci] * invv[b * L_ + t];
    a[row][ci] = v;
  }
  __syncthreads();
  int co = tid * 2;
  float acc0[8], acc1[8];
  #pragma unroll
  for (int j = 0; j < 8; ++j) { acc0[j] = 0.f; acc1[j] = 0.f; }
  for (int ci = 0; ci < C_; ++ci) {
    int4 wv = *(const int4*)(wq + ((((size_t)ci << 9) + co) << 3));
    float w0[7], w1[7];
    #pragma unroll
    for (int k = 0; k < 4; ++k) {
      w0[k] = (float)(int8_t)(wv.x >> (8 * k));
      w1[k] = (float)(int8_t)(wv.z >> (8 * k));
    }
    #pragma unroll
    for (int k = 0; k < 3; ++k) {
      w0[4 + k] = (float)(int8_t)(wv.y >> (8 * k));
      w1[4 + k] = (float)(int8_t)(wv.w >> (8 * k));
    }
    float av[14];
    #pragma unroll
    for (int r = 0; r < 14; ++r) av[r] = a[r][ci];
    #pragma unroll
    for (int j = 0; j < 8; ++j) {
      #pragma unroll
      for (int k = 0; k < 7; ++k) {
        acc0[j] = fmaf(av[j + k], w0[k], acc0[j]);
        acc1[j] = fmaf(av[j + k], w1[k], acc1[j]);
      }
    }
  }
  float mean = wsum[widx] * (1.0f / (float)NR);
  float M = fmaxf(mean, 1e-5f);
  float wscale = 1.0f / M;
  float dq = 1.0f / wscale;
  float b0 = bias[co], b1 = bias[co + 1];
  #pragma unroll
  for (int j = 0; j < 8; ++j) {
    size_t idx = (((size_t)b * L_ + t0 + j) << 9) + co;
    float y0 = acc0[j] * dq + b0;
    float y1 = acc1[j] * dq + b1;
    if (do_silu) {
      y0 = y0 / (1.0f + expf(-y0));
      y1 = y1 / (1.0f + expf(-y1));
    }
    if (res) {
      y0 += res[idx];
      y1 += res[idx + 1];
    }
    out[idx] = y0;
    out[idx + 1] = y1;
  }
}

// ---------------- LayerNorm over channels ----------------
__global__ void ln_kernel(const float* __restrict__ x, const float* __restrict__ g,
                          const float* __restrict__ be, float* __restrict__ out) {
  int tok = blockIdx.x;
  const float* row = x + (size_t)tok * C_;
  int tid = threadIdx.x;
  float v0 = row[tid];
  float v1 = row[tid + 256];
  float total = block_reduce_sum_256(v0 + v1);
  float mu = total * (1.0f / (float)C_);
  float d0 = v0 - mu, d1 = v1 - mu;
  float vs = block_reduce_sum_256(d0 * d0 + d1 * d1);
  float var = vs * (1.0f / (float)C_);
  float r = 1.0f / sqrtf(var + 1e-5f);
  size_t base = (size_t)tok * C_;
  out[base + tid] = d0 * r * g[tid] + be[tid];
  out[base + tid + 256] = d1 * r * g[tid + 256] + be[tid + 256];
}

// ---------------- launch ----------------

extern "C" void kernel_launch(void* const* d_in, const int* in_sizes, int n_in,
                              void* d_out, int out_size, void* d_ws, size_t ws_size,
                              hipStream_t stream) {
  const float* x    = (const float*)d_in[0];
  const float* w_up = (const float*)d_in[1];
  const float* b_up = (const float*)d_in[2];
  const float* w_r1 = (const float*)d_in[3];
  const float* b_r1 = (const float*)d_in[4];
  const float* w_r2 = (const float*)d_in[5];
  const float* b_r2 = (const float*)d_in[6];
  const float* ln_w = (const float*)d_in[7];
  const float* ln_b = (const float*)d_in[8];
  float* out = (float*)d_out;

  char* ws = (char*)d_ws;
  size_t off = 0;
  auto alloc = [&](size_t sz) { size_t p = off; off += (sz + 255) & ~(size_t)255; return p; };
  float*  wsum = (float*) (ws + alloc(256));
  int8_t* qx   = (int8_t*)(ws + alloc((size_t)B_ * T_ * C_));        // 2 MB
  float*  invx = (float*) (ws + alloc((size_t)B_ * T_ * 4));
  int8_t* wqup = (int8_t*)(ws + alloc((size_t)512 * 512 * 4));       // 1 MB
  int8_t* wq1  = (int8_t*)(ws + alloc((size_t)512 * 512 * 8));       // 2 MB (k-padded)
  int8_t* wq2  = (int8_t*)(ws + alloc((size_t)512 * 512 * 8));       // 2 MB
  float*  h    = (float*) (ws + alloc((size_t)B_ * L_ * C_ * 4));    // 16.8 MB
  int8_t* qh   = (int8_t*)(ws + alloc((size_t)B_ * L_ * C_));        // 4.2 MB
  float*  invh = (float*) (ws + alloc((size_t)B_ * L_ * 4));
  float*  r    = (float*) (ws + alloc((size_t)B_ * L_ * C_ * 4));    // 16.8 MB
  // total ~45 MB

  hipMemsetAsync(wsum, 0, 256, stream);

  abssum_kernel<<<256, 256, 0, stream>>>(w_up, NUP, wsum + 0);
  abssum_kernel<<<256, 256, 0, stream>>>(w_r1, NR, wsum + 1);
  abssum_kernel<<<256, 256, 0, stream>>>(w_r2, NR, wsum + 2);

  tern_up_kernel<<<NUP / 256, 256, 0, stream>>>(w_up, wqup, wsum);
  tern_7_kernel<<<NR / 256, 256, 0, stream>>>(w_r1, wq1, wsum, 1);
  tern_7_kernel<<<NR / 256, 256, 0, stream>>>(w_r2, wq2, wsum, 2);

  act_quant_kernel<<<B_ * T_, 256, 0, stream>>>(x, qx, invx);

  convt_kernel<<<B_ * (L_ / 8), 256, 0, stream>>>(qx, invx, wqup, wsum, b_up, h);

  act_quant_kernel<<<B_ * L_, 256, 0, stream>>>(h, qh, invh);

  conv7_kernel<<<B_ * (L_ / 8), 256, 0, stream>>>(qh, invh, wq1, wsum, 1, b_r1,
                                                  nullptr, 1, r);

  act_quant_kernel<<<B_ * L_, 256, 0, stream>>>(r, qh, invh);  // reuse qh/invh

  conv7_kernel<<<B_ * (L_ / 8), 256, 0, stream>>>(qh, invh, wq2, wsum, 2, b_r2,
                                                  h, 0, r);    // r now holds pre-LN

  ln_kernel<<<B_ * L_, 256, 0, stream>>>(r, ln_w, ln_b, out);
}

// Round 2
// 274.093 us; speedup vs baseline: 3.7167x; 3.7167x over previous
//
#include <hip/hip_runtime.h>
#include <hip/hip_bf16.h>
#include <cstdint>
#include <cstddef>

// LearnableUpsampler: quant -> convT(K=4,s=2) -> quant -> conv7+silu -> quant -> conv7 + res -> LN
// Round 1: int8 MFMA (v_mfma_i32_32x32x32_i8) per-tap GEMMs. Activations int8 per-token
// absmax quant (exact), weights ternary. Per-tap i32->fp32 fold with per-input-row scale.
// Weights/activations repacked to 16B-tile order so global_load_lds staging is contiguous.

#define B_ 2
#define T_ 2048
#define L_ 4096
#define C_ 512

static constexpr int NUP = 512 * 512 * 4;
static constexpr int NR  = 512 * 512 * 7;

using v4i  = __attribute__((ext_vector_type(4))) int;
using v16i = __attribute__((ext_vector_type(16))) int;

__device__ __forceinline__ void gl16(const void* g, void* l) {
  __builtin_amdgcn_global_load_lds((const __attribute__((address_space(1))) unsigned int*)g,
                                   (__attribute__((address_space(3))) unsigned int*)l,
                                   16, 0, 0);
}

// ---------------- reductions ----------------

__device__ inline float block_reduce_sum_256(float v) {
  #pragma unroll
  for (int off = 32; off > 0; off >>= 1) v += __shfl_down(v, off, 64);
  __shared__ float s[4];
  __syncthreads();
  if ((threadIdx.x & 63) == 0) s[threadIdx.x >> 6] = v;
  __syncthreads();
  return (s[0] + s[1]) + (s[2] + s[3]);
}

__global__ void abssum_kernel(const float* __restrict__ w, int n, float* __restrict__ out) {
  int idx = blockIdx.x * 256 + threadIdx.x;
  float s = 0.f;
  for (int i = idx; i < n; i += gridDim.x * 256) s += fabsf(w[i]);
  s = block_reduce_sum_256(s);
  if (threadIdx.x == 0) atomicAdd(out, s);
}

// ---------------- ternarize + repack to [tap][kc4][kq8][co512][16] ----------------
// conv7 weights: input w (co, ci, 7); tap = k (shift k-3 ascending)
__global__ void tern_7_kernel(const float* __restrict__ w, int8_t* __restrict__ o,
                              const float* __restrict__ wsum, int widx) {
  int idx = blockIdx.x * 256 + threadIdx.x;
  if (idx >= NR) return;
  float mean = wsum[widx] * (1.0f / (float)NR);
  float scale = 1.0f / fmaxf(mean, 1e-5f);
  float t = rintf(w[idx] * scale);
  t = fminf(fmaxf(t, -1.f), 1.f);
  int co = idx / 3584;
  int rem = idx - co * 3584;
  int ci = rem / 7;
  int k = rem - ci * 7;
  int kc = ci >> 7, kq = (ci >> 4) & 7, j = ci & 15;
  o[((((size_t)k * 4 + kc) * 8 + kq) * 512 + co) * 16 + j] = (int8_t)t;
}

// convT weights: input w (ci, co, 4); ptap order: parity0 {k=3,k=1}, parity1 {k=2,k=0}
__global__ void tern_up_kernel(const float* __restrict__ w, int8_t* __restrict__ o,
                               const float* __restrict__ wsum) {
  int idx = blockIdx.x * 256 + threadIdx.x;
  if (idx >= NUP) return;
  float mean = wsum[0] * (1.0f / (float)NUP);
  float scale = 1.0f / fmaxf(mean, 1e-5f);
  float t = rintf(w[idx] * scale);
  t = fminf(fmaxf(t, -1.f), 1.f);
  int ci = idx >> 11;
  int co = (idx >> 2) & 511;
  int k = idx & 3;
  int ptap = (k == 3) ? 0 : (k == 1) ? 1 : (k == 2) ? 2 : 3;
  int kc = ci >> 7, kq = (ci >> 4) & 7, j = ci & 15;
  o[((((size_t)ptap * 4 + kc) * 8 + kq) * 512 + co) * 16 + j] = (int8_t)t;
}

// ---------------- per-token activation quant; packed q layout [b][ci16(32)][LinH][16] ----------------
__global__ void act_quant_kernel(const float* __restrict__ x, int8_t* __restrict__ qd,
                                 float* __restrict__ inv, int Lb, int lbsh, int LinH) {
  int tok = blockIdx.x;
  int b = tok >> lbsh;
  int t = tok & (Lb - 1);
  const float* row = x + (size_t)tok * C_;
  int tid = threadIdx.x;
  float v0 = row[tid];
  float v1 = row[tid + 256];
  float m = fmaxf(fabsf(v0), fabsf(v1));
  #pragma unroll
  for (int off = 32; off > 0; off >>= 1) m = fmaxf(m, __shfl_down(m, off, 64));
  __shared__ float s[4];
  if ((tid & 63) == 0) s[tid >> 6] = m;
  __syncthreads();
  m = fmaxf(fmaxf(s[0], s[1]), fmaxf(s[2], s[3]));
  float scale = 127.0f / fmaxf(m, 1e-5f);
  float q0 = fminf(fmaxf(rintf(v0 * scale), -128.f), 127.f);
  float q1 = fminf(fmaxf(rintf(v1 * scale), -128.f), 127.f);
  int ci0 = tid, ci1 = tid + 256;
  qd[((size_t)(b * 32 + (ci0 >> 4)) * LinH + 8 + t) * 16 + (ci0 & 15)] = (int8_t)q0;
  qd[((size_t)(b * 32 + (ci1 >> 4)) * LinH + 8 + t) * 16 + (ci1 & 15)] = (int8_t)q1;
  if (tid == 0) inv[(size_t)b * LinH + 8 + t] = 1.0f / scale;
}

// ---------------- MFMA conv: per-tap int8 GEMM ----------------
// WG = 128 thr (2 waves). WG tile 64(M) x 128(N). Wave tile 64x64 = 2x2 of 32x32x32 i8.
// LDS A [kq8][row64][16], B [kq8][co128][16] per K=128 chunk; single-buffered (m97 style).
template<int NTAPS, bool CONVT>
__global__ __launch_bounds__(128, 2)
void conv_mfma(const int8_t* __restrict__ qin, const float* __restrict__ invp, int LinH,
               const int8_t* __restrict__ wq, const float* __restrict__ wsum, int widx,
               float wninv, const float* __restrict__ bias, const float* __restrict__ res,
               float* __restrict__ outp, int Lout, int do_silu) {
  __shared__ __align__(16) int8_t sA[8192];
  __shared__ __align__(16) int8_t sB[16384];
  __shared__ float sInv[80];

  const int tid = threadIdx.x;
  const int w = tid >> 6, lane = tid & 63, q = lane >> 5, l31 = lane & 31;
  const int n0 = (blockIdx.x & 3) * 128;
  const int t0 = (blockIdx.x >> 2) * 64;
  const int b = blockIdx.y;
  int s0 = -3;
  const int8_t* wq_p = wq;
  float* out_b = outp + (size_t)b * Lout * 512;
  int rstride = 512;
  if (CONVT) {
    int parity = blockIdx.z;
    s0 = parity - 1;
    wq_p += (size_t)parity * 2 * 4 * 8 * 512 * 16;
    out_b += parity * 512;
    rstride = 1024;
  }
  const int8_t* qin_b = qin + (size_t)b * 32 * LinH * 16;
  const float* inv_b = invp + (size_t)b * LinH + 8;

  if (tid < 80) sInv[tid] = inv_b[t0 - 8 + tid];

  v16i acc[2][2];
  float fs[2][2][16];
  #pragma unroll
  for (int mt = 0; mt < 2; ++mt)
    #pragma unroll
    for (int nt = 0; nt < 2; ++nt)
      #pragma unroll
      for (int r = 0; r < 16; ++r) { acc[mt][nt][r] = 0; fs[mt][nt][r] = 0.f; }

  for (int tap = 0; tap < NTAPS; ++tap) {
    const int shift = s0 + tap;
    for (int kc = 0; kc < 4; ++kc) {
      // stage A: 512 x 16B units, layout [kq][row][16]
      #pragma unroll
      for (int i = 0; i < 4; ++i) {
        int u0 = w * 64 + i * 128;
        int uu = u0 + lane;
        int kq = uu >> 6, row = uu & 63;
        const int8_t* g = qin_b + ((size_t)(kc * 8 + kq) * LinH + (size_t)(8 + t0 + shift + row)) * 16;
        gl16(g, sA + u0 * 16);
      }
      // stage B: 1024 x 16B units, layout [kq][co][16]
      const int8_t* wt = wq_p + (size_t)((tap * 4 + kc) * 8) * 512 * 16;
      #pragma unroll
      for (int i = 0; i < 8; ++i) {
        int u0 = w * 64 + i * 128;
        int uu = u0 + lane;
        int kq = uu >> 7, co = uu & 127;
        const int8_t* g = wt + ((size_t)kq * 512 + n0 + co) * 16;
        gl16(g, sB + u0 * 16);
      }
      __syncthreads();
      #pragma unroll
      for (int kk = 0; kk < 4; ++kk) {
        int arow = (kk * 2 + q) * 64;
        v4i a0 = *(const v4i*)(sA + (size_t)(arow + l31) * 16);
        v4i a1 = *(const v4i*)(sA + (size_t)(arow + 32 + l31) * 16);
        int brow = (kk * 2 + q) * 128 + w * 64;
        v4i b0 = *(const v4i*)(sB + (size_t)(brow + l31) * 16);
        v4i b1 = *(const v4i*)(sB + (size_t)(brow + 32 + l31) * 16);
        acc[0][0] = __builtin_amdgcn_mfma_i32_32x32x32_i8(a0, b0, acc[0][0], 0, 0, 0);
        acc[0][1] = __builtin_amdgcn_mfma_i32_32x32x32_i8(a0, b1, acc[0][1], 0, 0, 0);
        acc[1][0] = __builtin_amdgcn_mfma_i32_32x32x32_i8(a1, b0, acc[1][0], 0, 0, 0);
        acc[1][1] = __builtin_amdgcn_mfma_i32_32x32x32_i8(a1, b1, acc[1][1], 0, 0, 0);
      }
      __syncthreads();
    }
    // fold i32 -> fp32 with per-input-row scale; re-zero acc
    #pragma unroll
    for (int mt = 0; mt < 2; ++mt)
      #pragma unroll
      for (int rg = 0; rg < 4; ++rg)
        #pragma unroll
        for (int e = 0; e < 4; ++e) {
          float sc = sInv[8 + shift + mt * 32 + rg * 8 + q * 4 + e];
          int r = rg * 4 + e;
          fs[mt][0][r] = fmaf((float)acc[mt][0][r], sc, fs[mt][0][r]);
          fs[mt][1][r] = fmaf((float)acc[mt][1][r], sc, fs[mt][1][r]);
          acc[mt][0][r] = 0;
          acc[mt][1][r] = 0;
        }
  }

  float wdq = fmaxf(wsum[widx] * wninv, 1e-5f);
  #pragma unroll
  for (int nt = 0; nt < 2; ++nt) {
    int col = n0 + w * 64 + nt * 32 + l31;
    float bv = bias[col];
    #pragma unroll
    for (int mt = 0; mt < 2; ++mt)
      #pragma unroll
      for (int r = 0; r < 16; ++r) {
        int row = t0 + mt * 32 + (r & 3) + 8 * (r >> 2) + 4 * q;
        float y = fs[mt][nt][r] * wdq + bv;
        if (do_silu) y = y / (1.0f + expf(-y));
        if (res) y += res[(size_t)b * Lout * 512 + (size_t)row * 512 + col];
        out_b[(size_t)row * rstride + col] = y;
      }
  }
}

// ---------------- LayerNorm over channels ----------------
__global__ void ln_kernel(const float* __restrict__ x, const float* __restrict__ g,
                          const float* __restrict__ be, float* __restrict__ out) {
  int tok = blockIdx.x;
  const float* row = x + (size_t)tok * C_;
  int tid = threadIdx.x;
  float v0 = row[tid];
  float v1 = row[tid + 256];
  float total = block_reduce_sum_256(v0 + v1);
  float mu = total * (1.0f / (float)C_);
  float d0 = v0 - mu, d1 = v1 - mu;
  float vs = block_reduce_sum_256(d0 * d0 + d1 * d1);
  float var = vs * (1.0f / (float)C_);
  float r = 1.0f / sqrtf(var + 1e-5f);
  size_t base = (size_t)tok * C_;
  out[base + tid] = d0 * r * g[tid] + be[tid];
  out[base + tid + 256] = d1 * r * g[tid + 256] + be[tid + 256];
}

// ---------------- launch ----------------

extern "C" void kernel_launch(void* const* d_in, const int* in_sizes, int n_in,
                              void* d_out, int out_size, void* d_ws, size_t ws_size,
                              hipStream_t stream) {
  const float* x    = (const float*)d_in[0];
  const float* w_up = (const float*)d_in[1];
  const float* b_up = (const float*)d_in[2];
  const float* w_r1 = (const float*)d_in[3];
  const float* b_r1 = (const float*)d_in[4];
  const float* w_r2 = (const float*)d_in[5];
  const float* b_r2 = (const float*)d_in[6];
  const float* ln_w = (const float*)d_in[7];
  const float* ln_b = (const float*)d_in[8];
  float* out = (float*)d_out;

  const int LXH = T_ + 16;   // 2064 rows per batch (halo 8 each side)
  const int LHH = L_ + 16;   // 4112

  char* ws = (char*)d_ws;
  size_t off = 0;
  auto alloc = [&](size_t sz) { size_t p = off; off += (sz + 255) & ~(size_t)255; return p; };
  float*  wsum = (float*) (ws + alloc(256));
  int8_t* qx   = (int8_t*)(ws + alloc((size_t)B_ * 32 * LXH * 16));   // 2.1 MB
  float*  invx = (float*) (ws + alloc((size_t)B_ * LXH * 4));
  int8_t* wqup = (int8_t*)(ws + alloc((size_t)4 * 4 * 8 * 512 * 16)); // 1 MB
  int8_t* wq1  = (int8_t*)(ws + alloc((size_t)7 * 4 * 8 * 512 * 16)); // 1.8 MB
  int8_t* wq2  = (int8_t*)(ws + alloc((size_t)7 * 4 * 8 * 512 * 16)); // 1.8 MB
  float*  h    = (float*) (ws + alloc((size_t)B_ * L_ * C_ * 4));     // 16.8 MB
  int8_t* qh   = (int8_t*)(ws + alloc((size_t)B_ * 32 * LHH * 16));   // 4.2 MB
  float*  invh = (float*) (ws + alloc((size_t)B_ * LHH * 4));
  float*  r    = (float*) (ws + alloc((size_t)B_ * L_ * C_ * 4));     // 16.8 MB

  hipMemsetAsync(wsum, 0, 256, stream);
  hipMemsetAsync(qx, 0, (size_t)B_ * 32 * LXH * 16, stream);  // zero halos (whole buffer)
  hipMemsetAsync(qh, 0, (size_t)B_ * 32 * LHH * 16, stream);

  abssum_kernel<<<256, 256, 0, stream>>>(w_up, NUP, wsum + 0);
  abssum_kernel<<<256, 256, 0, stream>>>(w_r1, NR, wsum + 1);
  abssum_kernel<<<256, 256, 0, stream>>>(w_r2, NR, wsum + 2);

  tern_up_kernel<<<NUP / 256, 256, 0, stream>>>(w_up, wqup, wsum);
  tern_7_kernel<<<NR / 256, 256, 0, stream>>>(w_r1, wq1, wsum, 1);
  tern_7_kernel<<<NR / 256, 256, 0, stream>>>(w_r2, wq2, wsum, 2);

  act_quant_kernel<<<B_ * T_, 256, 0, stream>>>(x, qx, invx, T_, 11, LXH);

  // convT: grid (4 ntiles * 32 mtiles, B, parity)
  conv_mfma<2, true><<<dim3(4 * 32, B_, 2), 128, 0, stream>>>(
      qx, invx, LXH, wqup, wsum, 0, 1.0f / (float)NUP, b_up, nullptr, h, L_, 0);

  act_quant_kernel<<<B_ * L_, 256, 0, stream>>>(h, qh, invh, L_, 12, LHH);

  conv_mfma<7, false><<<dim3(4 * 64, B_, 1), 128, 0, stream>>>(
      qh, invh, LHH, wq1, wsum, 1, 1.0f / (float)NR, b_r1, nullptr, r, L_, 1);

  act_quant_kernel<<<B_ * L_, 256, 0, stream>>>(r, qh, invh, L_, 12, LHH);

  conv_mfma<7, false><<<dim3(4 * 64, B_, 1), 128, 0, stream>>>(
      qh, invh, LHH, wq2, wsum, 2, 1.0f / (float)NR, b_r2, h, r, L_, 0);

  ln_kernel<<<B_ * L_, 256, 0, stream>>>(r, ln_w, ln_b, out);
}